// Round 3
// baseline (22999.182 us; speedup 1.0000x reference)
//
#include <hip/hip_runtime.h>

#define VOCAB 32000
#define EMBD  512
#define HIDD  1024
#define SLEN  512
#define NBAT  4
#define GATE4 4096   // 4*HIDD
#define LBLK  128    // lstm blocks; each owns UPB hidden units
#define UPB   8      // units per block

// ---------------- embedding gather ----------------
__global__ void embed_k(const int* __restrict__ ids, const float* __restrict__ emb,
                        float* __restrict__ X0) {
  const int n  = blockIdx.x;             // 0..2047 (= b*SLEN + s)
  const int id = ids[n];
  ((float4*)X0)[(size_t)n*(EMBD/4) + threadIdx.x] =
      ((const float4*)emb)[(size_t)id*(EMBD/4) + threadIdx.x];
}

// ---------------- 32x32 tiled transpose: dst[c][r] = src[r][c] ----------------
// src [1024][4096] row-major -> dst [4096][1024]
__global__ __launch_bounds__(256) void transpose_k(const float* __restrict__ src,
                                                   float* __restrict__ dst) {
  __shared__ float t[32][33];
  const int bx = blockIdx.x * 32;   // col base (0..4095)
  const int by = blockIdx.y * 32;   // row base (0..1023)
  const int r0 = threadIdx.x >> 5;  // 0..7
  const int c  = threadIdx.x & 31;
  #pragma unroll
  for (int i = 0; i < 4; i++) {
    const int r = r0 + i*8;
    t[r][c] = src[(size_t)(by + r)*GATE4 + bx + c];
  }
  __syncthreads();
  #pragma unroll
  for (int i = 0; i < 4; i++) {
    const int rw = r0 + i*8;
    dst[(size_t)(bx + rw)*HIDD + by + c] = t[c][rw];
  }
}

// ---------------- f32 tiled GEMM: C = A@B + bias ----------------
// A [M,K] rm, B [K,N] rm, bias[N]; 64x64 tile, BK=16, 256 threads, 4x4/thread
__global__ __launch_bounds__(256) void gemm_nn_bias(
    const float* __restrict__ A, const float* __restrict__ B,
    const float* __restrict__ bias, float* __restrict__ C,
    int M, int N, int K) {
  __shared__ float As[16][64];
  __shared__ float Bs[16][64];
  const int tid = threadIdx.x;
  const int bm = blockIdx.y * 64;
  const int bn = blockIdx.x * 64;
  const int tx = tid & 15, ty = tid >> 4;
  const int mA = tid >> 2, kqA = (tid & 3) * 4;
  const int kB = tid >> 4, nB = (tid & 15) * 4;
  float acc[4][4] = {{0.f}};
  for (int k0 = 0; k0 < K; k0 += 16) {
    float4 a4 = *(const float4*)(A + (size_t)(bm + mA)*K + k0 + kqA);
    As[kqA+0][mA] = a4.x; As[kqA+1][mA] = a4.y;
    As[kqA+2][mA] = a4.z; As[kqA+3][mA] = a4.w;
    *(float4*)&Bs[kB][nB] = *(const float4*)(B + (size_t)(k0 + kB)*N + bn + nB);
    __syncthreads();
    #pragma unroll
    for (int k = 0; k < 16; k++) {
      float4 av = *(float4*)&As[k][ty*4];
      float4 bv = *(float4*)&Bs[k][tx*4];
      float ar[4] = {av.x, av.y, av.z, av.w};
      float br[4] = {bv.x, bv.y, bv.z, bv.w};
      #pragma unroll
      for (int i = 0; i < 4; i++)
        #pragma unroll
        for (int j = 0; j < 4; j++)
          acc[i][j] += ar[i] * br[j];
    }
    __syncthreads();
  }
  float4 bi = *(const float4*)(bias + bn + tx*4);
  #pragma unroll
  for (int i = 0; i < 4; i++) {
    float4 o;
    o.x = acc[i][0] + bi.x; o.y = acc[i][1] + bi.y;
    o.z = acc[i][2] + bi.z; o.w = acc[i][3] + bi.w;
    *(float4*)(C + (size_t)(bm + ty*4 + i)*N + bn + tx*4) = o;
  }
}

// ---------------- logits GEMM: C = A @ Bt^T, with pad-mask ----------------
__global__ __launch_bounds__(256) void gemm_nt_logits(
    const float* __restrict__ A,   // P [2048, 512] (in d_ws — must NOT alias C)
    const float* __restrict__ Bt,  // emb [32000, 512]
    const int* __restrict__ ids,   // [2048]
    float* __restrict__ C) {       // [2048, 32000]
  const int K = EMBD, N = VOCAB;
  __shared__ float As[16][64];
  __shared__ float Bs[16][64];
  const int tid = threadIdx.x;
  const int bm = blockIdx.y * 64;
  const int bn = blockIdx.x * 64;
  const int tx = tid & 15, ty = tid >> 4;
  const int rA = tid >> 2, kq = (tid & 3) * 4;
  float acc[4][4] = {{0.f}};
  for (int k0 = 0; k0 < K; k0 += 16) {
    float4 a4 = *(const float4*)(A  + (size_t)(bm + rA)*K + k0 + kq);
    float4 b4 = *(const float4*)(Bt + (size_t)(bn + rA)*K + k0 + kq);
    As[kq+0][rA] = a4.x; As[kq+1][rA] = a4.y; As[kq+2][rA] = a4.z; As[kq+3][rA] = a4.w;
    Bs[kq+0][rA] = b4.x; Bs[kq+1][rA] = b4.y; Bs[kq+2][rA] = b4.z; Bs[kq+3][rA] = b4.w;
    __syncthreads();
    #pragma unroll
    for (int k = 0; k < 16; k++) {
      float4 av = *(float4*)&As[k][ty*4];
      float4 bv = *(float4*)&Bs[k][tx*4];
      float ar[4] = {av.x, av.y, av.z, av.w};
      float br[4] = {bv.x, bv.y, bv.z, bv.w};
      #pragma unroll
      for (int i = 0; i < 4; i++)
        #pragma unroll
        for (int j = 0; j < 4; j++)
          acc[i][j] += ar[i] * br[j];
    }
    __syncthreads();
  }
  #pragma unroll
  for (int i = 0; i < 4; i++) {
    const int row = bm + ty*4 + i;
    const bool mk = ids[row] != 0;
    float4 o;
    if (mk) { o.x = acc[i][0]; o.y = acc[i][1]; o.z = acc[i][2]; o.w = acc[i][3]; }
    else    { o.x = (bn + tx*4 == 0) ? 1.f : 0.f; o.y = 0.f; o.z = 0.f; o.w = 0.f; }
    *(float4*)(C + (size_t)row*N + bn + tx*4) = o;
  }
}

// ---------------- persistent LSTM recurrence ----------------
// LBLK=128 blocks x 256 threads; block j owns hidden units [8j, 8j+8) ->
// 32 gate columns of Wr, held in VGPRs (128 f32/thread, loaded coalesced
// from the pre-transposed WrT [4096][1024]). Each step:
//   z = h(t-1) @ Wr_block  (K=1024 dot, reduced via in-wave butterfly)
//   gates -> h(t), c(t)  (c lives in registers of the 32 gate threads)
//   h(t) -> H[:, t, :]; distributed-flag device barrier; reload h(t) to LDS.
__device__ __forceinline__ int rev5(int l) {
  return ((l & 1) << 4) | ((l & 2) << 2) | (l & 4) | ((l & 8) >> 2) | ((l & 16) >> 4);
}

__global__ __launch_bounds__(256, 1) void lstm_rec(
    const float* __restrict__ Z,    // [B*S, 4096] precomputed x@Wk + b
    const float* __restrict__ WrT,  // [4096, 1024] transposed recurrent weights
    const int* __restrict__ ids,    // [B*S]
    float* __restrict__ H,          // [B*S, 1024] output h sequence
    volatile unsigned* bar) {       // LBLK flags, stride 16 u32 (64B apart)
  __shared__ float h_s[NBAT * HIDD];   // [b][k]
  __shared__ float z_s[4][64];
  __shared__ float zc[128];            // [cc][b]  cc=0..31, b=0..3
  const int tid  = threadIdx.x;
  const int lane = tid & 63;
  const int w    = tid >> 6;
  const int ccH  = tid >> 7;           // 0..1  (which 16 of the 32 gate cols)
  const int part = tid & 127;          // 0..127 (k-slice owner: 8 k values)
  const int hbase = blockIdx.x * UPB;

  // --- coalesced load of this block's 32 WrT rows into registers ---
  float4 Wf[16], Wg[16];
  #pragma unroll
  for (int cl = 0; cl < 16; cl++) {
    const int cc  = ccH * 16 + cl;
    const int g   = cc >> 3, d = cc & 7;
    const size_t col = (size_t)(g * HIDD + hbase + d);
    Wf[cl] = *(const float4*)(WrT + col * HIDD + 4 * part);
    Wg[cl] = *(const float4*)(WrT + col * HIDD + 512 + 4 * part);
  }
  float c_reg = 0.f;   // cell state, meaningful in threads tid<32
  for (int i = tid; i < NBAT * HIDD; i += 256) h_s[i] = 0.f;
  __syncthreads();

  for (int t = 0; t < SLEN; t++) {
    // ---- partial dots: a[cl*4+b] over this thread's 8 k values ----
    float4 ha[NBAT], hb[NBAT];
    #pragma unroll
    for (int b = 0; b < NBAT; b++) {
      ha[b] = ((const float4*)h_s)[b*256 + part];        // k = 4*part..+3
      hb[b] = ((const float4*)h_s)[b*256 + 128 + part];  // k = 512+4*part..+3
    }
    float a[64];
    #pragma unroll
    for (int cl = 0; cl < 16; cl++) {
      #pragma unroll
      for (int b = 0; b < NBAT; b++) {
        a[cl*4 + b] = Wf[cl].x*ha[b].x + Wf[cl].y*ha[b].y
                    + Wf[cl].z*ha[b].z + Wf[cl].w*ha[b].w
                    + Wg[cl].x*hb[b].x + Wg[cl].y*hb[b].y
                    + Wg[cl].z*hb[b].z + Wg[cl].w*hb[b].w;
      }
    }
    // ---- in-wave reduction: fold lanes 32..63, then 5 halving stages ----
    #pragma unroll
    for (int i = 0; i < 64; i++) a[i] += __shfl_xor(a[i], 32);
#define HALVE(MASK, SH, HSZ)                          \
    { const int bit_ = (lane >> SH) & 1;              \
      _Pragma("unroll")                               \
      for (int j = 0; j < HSZ; j++) {                 \
        float snd = bit_ ? a[j] : a[j + HSZ];         \
        float kep = bit_ ? a[j + HSZ] : a[j];         \
        a[j] = kep + __shfl_xor(snd, MASK);           \
      } }
    HALVE(1, 0, 32) HALVE(2, 1, 16) HALVE(4, 2, 8) HALVE(8, 3, 4) HALVE(16, 4, 2)
#undef HALVE
    if (lane < 32) {   // lane holds totals for acc idx rev5*2 and rev5*2+1
      z_s[w][rev5(lane)*2 + 0] = a[0];
      z_s[w][rev5(lane)*2 + 1] = a[1];
    }
    __syncthreads();
    if (tid < 128) {  // combine the two waves per ccH: zc[cc*4+b]
      const int cc = tid >> 2, b = tid & 3;
      const int cH = cc >> 4, i = ((cc & 15) << 2) | b;
      zc[tid] = z_s[2*cH][i] + z_s[2*cH + 1][i];
    }
    __syncthreads();
    if (tid < 32) {  // gates for (b, d): 8 units x 4 batches
      const int b = tid >> 3, d = tid & 7;
      const float* zrow = Z + (size_t)(b*SLEN + t) * GATE4;
      const float zi = zc[((0*8 + d) << 2) + b] + zrow[0*HIDD + hbase + d];
      const float zf = zc[((1*8 + d) << 2) + b] + zrow[1*HIDD + hbase + d];
      const float zg = zc[((2*8 + d) << 2) + b] + zrow[2*HIDD + hbase + d];
      const float zo = zc[((3*8 + d) << 2) + b] + zrow[3*HIDD + hbase + d];
      const float ig = 1.f / (1.f + expf(-zi));
      const float fg = 1.f / (1.f + expf(-zf));
      const float gg = tanhf(zg);
      const float og = 1.f / (1.f + expf(-zo));
      const float cn = fg * c_reg + ig * gg;
      const float hn = og * tanhf(cn);
      const bool mk = ids[b*SLEN + t] != 0;
      const float hp = h_s[b*HIDD + hbase + d];
      const float ho = mk ? hn : hp;
      c_reg = mk ? cn : c_reg;
      H[(size_t)(b*SLEN + t) * HIDD + hbase + d] = ho;
    }
    if (t == SLEN - 1) break;
    // ---- distributed-flag device barrier ----
    __syncthreads();
    if (tid == 0) {
      __threadfence();  // release: make this block's H stores visible
      __hip_atomic_store((unsigned*)&bar[blockIdx.x * 16], (unsigned)(t + 1),
                         __ATOMIC_RELEASE, __HIP_MEMORY_SCOPE_AGENT);
    }
    if (tid < LBLK) {
      while (__hip_atomic_load((unsigned*)&bar[tid * 16],
                               __ATOMIC_ACQUIRE, __HIP_MEMORY_SCOPE_AGENT)
             < (unsigned)(t + 1)) {
        __builtin_amdgcn_s_sleep(2);
      }
    }
    __syncthreads();
    __threadfence();  // acquire side: discard stale cached H lines
    // ---- reload full h(t) into LDS ----
    #pragma unroll
    for (int r = 0; r < 4; r++) {
      const int i4 = tid + r*256;
      const int b = i4 >> 8, k4 = i4 & 255;
      ((float4*)h_s)[b*256 + k4] =
          *(const float4*)(H + (size_t)(b*SLEN + t) * HIDD + k4*4);
    }
    __syncthreads();
  }
}

extern "C" void kernel_launch(void* const* d_in, const int* in_sizes, int n_in,
                              void* d_out, int out_size, void* d_ws, size_t ws_size,
                              hipStream_t stream) {
  const int*   ids = (const int*)  d_in[0];
  const float* emb = (const float*)d_in[1];
  const float* Wk0 = (const float*)d_in[2];
  const float* Wr0 = (const float*)d_in[3];
  const float* b0  = (const float*)d_in[4];
  const float* Wk1 = (const float*)d_in[5];
  const float* Wr1 = (const float*)d_in[6];
  const float* b1  = (const float*)d_in[7];
  const float* Wp  = (const float*)d_in[8];
  const float* bp  = (const float*)d_in[9];
  float* out = (float*)d_out;

  // Intermediates that are DEAD before gemm_nt_logits launches live in the
  // head of d_out. P and the barrier flags are live while C is being written
  // (or are tiny) -> they live in d_ws (needs ~4.2 MB).
  float* X0   = out;                  // [2048,  512]  1,048,576 f
  float* Z    = out + 1048576;        // [2048, 4096]  8,388,608 f (reused L0/L1)
  float* H0   = out + 9437184;        // [2048, 1024]  2,097,152 f
  float* H1   = out + 11534336;       // [2048, 1024]  2,097,152 f
  float* WrT0 = out + 13631488;       // [4096, 1024]  4,194,304 f
  float* WrT1 = out + 17825792;       // [4096, 1024]  4,194,304 f
  unsigned* bar = (unsigned*)d_ws;    // 2 x LBLK x 16 u32 = 16 KB
  float* P    = ((float*)d_ws) + 4096;  // [2048, 512]  1,048,576 f = 4 MB

  hipMemsetAsync(bar, 0, 2 * LBLK * 16 * sizeof(unsigned), stream);
  embed_k<<<2048, 128, 0, stream>>>(ids, emb, X0);
  transpose_k<<<dim3(128, 32), 256, 0, stream>>>(Wr0, WrT0);
  transpose_k<<<dim3(128, 32), 256, 0, stream>>>(Wr1, WrT1);
  gemm_nn_bias<<<dim3(64, 32), 256, 0, stream>>>(X0, Wk0, b0, Z, 2048, 4096, 512);
  lstm_rec<<<LBLK, 256, 0, stream>>>(Z, WrT0, ids, H0, bar);
  gemm_nn_bias<<<dim3(64, 32), 256, 0, stream>>>(H0, Wk1, b1, Z, 2048, 4096, 1024);
  lstm_rec<<<LBLK, 256, 0, stream>>>(Z, WrT1, ids, H1, bar + LBLK * 16);
  gemm_nn_bias<<<dim3(8, 32), 256, 0, stream>>>(H1, Wp, bp, P, 2048, 512, 1024);
  gemm_nt_logits<<<dim3(500, 32), 256, 0, stream>>>(P, emb, ids, out);
}

// Round 4
// 9450.693 us; speedup vs baseline: 2.4336x; 2.4336x over previous
//
#include <hip/hip_runtime.h>

#define VOCAB 32000
#define EMBD  512
#define HIDD  1024
#define SLEN  512
#define NBAT  4
#define GATE4 4096   // 4*HIDD
#define LBLK  128    // lstm blocks; each owns UPB hidden units
#define UPB   8      // units per block

typedef unsigned long long u64;

// ---------------- embedding gather ----------------
__global__ void embed_k(const int* __restrict__ ids, const float* __restrict__ emb,
                        float* __restrict__ X0) {
  const int n  = blockIdx.x;             // 0..2047 (= b*SLEN + s)
  const int id = ids[n];
  ((float4*)X0)[(size_t)n*(EMBD/4) + threadIdx.x] =
      ((const float4*)emb)[(size_t)id*(EMBD/4) + threadIdx.x];
}

// ---------------- 32x32 tiled transpose: dst[c][r] = src[r][c] ----------------
// src [1024][4096] row-major -> dst [4096][1024]
__global__ __launch_bounds__(256) void transpose_k(const float* __restrict__ src,
                                                   float* __restrict__ dst) {
  __shared__ float t[32][33];
  const int bx = blockIdx.x * 32;   // col base (0..4095)
  const int by = blockIdx.y * 32;   // row base (0..1023)
  const int r0 = threadIdx.x >> 5;  // 0..7
  const int c  = threadIdx.x & 31;
  #pragma unroll
  for (int i = 0; i < 4; i++) {
    const int r = r0 + i*8;
    t[r][c] = src[(size_t)(by + r)*GATE4 + bx + c];
  }
  __syncthreads();
  #pragma unroll
  for (int i = 0; i < 4; i++) {
    const int rw = r0 + i*8;
    dst[(size_t)(bx + rw)*HIDD + by + c] = t[c][rw];
  }
}

// ---------------- f32 tiled GEMM: C = A@B + bias ----------------
// A [M,K] rm, B [K,N] rm, bias[N]; 64x64 tile, BK=16, 256 threads, 4x4/thread
__global__ __launch_bounds__(256) void gemm_nn_bias(
    const float* __restrict__ A, const float* __restrict__ B,
    const float* __restrict__ bias, float* __restrict__ C,
    int M, int N, int K) {
  __shared__ float As[16][64];
  __shared__ float Bs[16][64];
  const int tid = threadIdx.x;
  const int bm = blockIdx.y * 64;
  const int bn = blockIdx.x * 64;
  const int tx = tid & 15, ty = tid >> 4;
  const int mA = tid >> 2, kqA = (tid & 3) * 4;
  const int kB = tid >> 4, nB = (tid & 15) * 4;
  float acc[4][4] = {{0.f}};
  for (int k0 = 0; k0 < K; k0 += 16) {
    float4 a4 = *(const float4*)(A + (size_t)(bm + mA)*K + k0 + kqA);
    As[kqA+0][mA] = a4.x; As[kqA+1][mA] = a4.y;
    As[kqA+2][mA] = a4.z; As[kqA+3][mA] = a4.w;
    *(float4*)&Bs[kB][nB] = *(const float4*)(B + (size_t)(k0 + kB)*N + bn + nB);
    __syncthreads();
    #pragma unroll
    for (int k = 0; k < 16; k++) {
      float4 av = *(float4*)&As[k][ty*4];
      float4 bv = *(float4*)&Bs[k][tx*4];
      float ar[4] = {av.x, av.y, av.z, av.w};
      float br[4] = {bv.x, bv.y, bv.z, bv.w};
      #pragma unroll
      for (int i = 0; i < 4; i++)
        #pragma unroll
        for (int j = 0; j < 4; j++)
          acc[i][j] += ar[i] * br[j];
    }
    __syncthreads();
  }
  float4 bi = *(const float4*)(bias + bn + tx*4);
  #pragma unroll
  for (int i = 0; i < 4; i++) {
    float4 o;
    o.x = acc[i][0] + bi.x; o.y = acc[i][1] + bi.y;
    o.z = acc[i][2] + bi.z; o.w = acc[i][3] + bi.w;
    *(float4*)(C + (size_t)(bm + ty*4 + i)*N + bn + tx*4) = o;
  }
}

// ---------------- logits GEMM: C = A @ Bt^T, with pad-mask ----------------
__global__ __launch_bounds__(256) void gemm_nt_logits(
    const float* __restrict__ A,   // P [2048, 512] (in d_ws — must NOT alias C)
    const float* __restrict__ Bt,  // emb [32000, 512]
    const int* __restrict__ ids,   // [2048]
    float* __restrict__ C) {       // [2048, 32000]
  const int K = EMBD, N = VOCAB;
  __shared__ float As[16][64];
  __shared__ float Bs[16][64];
  const int tid = threadIdx.x;
  const int bm = blockIdx.y * 64;
  const int bn = blockIdx.x * 64;
  const int tx = tid & 15, ty = tid >> 4;
  const int rA = tid >> 2, kq = (tid & 3) * 4;
  float acc[4][4] = {{0.f}};
  for (int k0 = 0; k0 < K; k0 += 16) {
    float4 a4 = *(const float4*)(A  + (size_t)(bm + rA)*K + k0 + kq);
    float4 b4 = *(const float4*)(Bt + (size_t)(bn + rA)*K + k0 + kq);
    As[kq+0][rA] = a4.x; As[kq+1][rA] = a4.y; As[kq+2][rA] = a4.z; As[kq+3][rA] = a4.w;
    Bs[kq+0][rA] = b4.x; Bs[kq+1][rA] = b4.y; Bs[kq+2][rA] = b4.z; Bs[kq+3][rA] = b4.w;
    __syncthreads();
    #pragma unroll
    for (int k = 0; k < 16; k++) {
      float4 av = *(float4*)&As[k][ty*4];
      float4 bv = *(float4*)&Bs[k][tx*4];
      float ar[4] = {av.x, av.y, av.z, av.w};
      float br[4] = {bv.x, bv.y, bv.z, bv.w};
      #pragma unroll
      for (int i = 0; i < 4; i++)
        #pragma unroll
        for (int j = 0; j < 4; j++)
          acc[i][j] += ar[i] * br[j];
    }
    __syncthreads();
  }
  #pragma unroll
  for (int i = 0; i < 4; i++) {
    const int row = bm + ty*4 + i;
    const bool mk = ids[row] != 0;
    float4 o;
    if (mk) { o.x = acc[i][0]; o.y = acc[i][1]; o.z = acc[i][2]; o.w = acc[i][3]; }
    else    { o.x = (bn + tx*4 == 0) ? 1.f : 0.f; o.y = 0.f; o.z = 0.f; o.w = 0.f; }
    *(float4*)(C + (size_t)row*N + bn + tx*4) = o;
  }
}

// ---------------- persistent LSTM recurrence (fence-free tagged exchange) ----
// LBLK=128 blocks x 256 threads; block j owns hidden units [8j, 8j+8) ->
// 32 gate columns of Wr in VGPRs. Cross-block h exchange: each h value is a
// 64-bit word (tag<<32 | f32 bits) moved with RELAXED agent-scope atomics
// (single-copy atomic => tag+value arrive together; no fences, no cache
// flush/invalidate storms). Readers spin until tag matches. Two slots by
// step parity make producer-one-step-ahead overwrites safe. t=0 skips the
// gather (h(-1)=0), so no initialization of Hx is needed (poison-safe).
__device__ __forceinline__ int rev5(int l) {
  return ((l & 1) << 4) | ((l & 2) << 2) | (l & 4) | ((l & 8) >> 2) | ((l & 16) >> 4);
}

__global__ __launch_bounds__(256, 1) void lstm_rec(
    const float* __restrict__ Z,    // [B*S, 4096] precomputed x@Wk + b
    const float* __restrict__ WrT,  // [4096, 1024] transposed recurrent weights
    const int* __restrict__ ids,    // [B*S]
    float* __restrict__ H,          // [B*S, 1024] output h sequence
    u64* __restrict__ Hx,           // [2][NBAT*HIDD] tagged h exchange
    int tagbase) {                  // 0 for layer 0, SLEN for layer 1
  __shared__ float h_s[NBAT * HIDD];   // [b][k]
  __shared__ float z_s[4][64];
  __shared__ float zc[128];            // [cc][b]  cc=0..31, b=0..3
  const int tid  = threadIdx.x;
  const int lane = tid & 63;
  const int w    = tid >> 6;
  const int ccH  = tid >> 7;           // 0..1  (which 16 of the 32 gate cols)
  const int part = tid & 127;          // 0..127 (k-slice owner: 8 k values)
  const int hbase = blockIdx.x * UPB;

  // --- coalesced load of this block's 32 WrT rows into registers ---
  float4 Wf[16], Wg[16];
  #pragma unroll
  for (int cl = 0; cl < 16; cl++) {
    const int cc  = ccH * 16 + cl;
    const int g   = cc >> 3, d = cc & 7;
    const size_t col = (size_t)(g * HIDD + hbase + d);
    Wf[cl] = *(const float4*)(WrT + col * HIDD + 4 * part);
    Wg[cl] = *(const float4*)(WrT + col * HIDD + 512 + 4 * part);
  }
  float c_reg = 0.f;   // cell state, meaningful in threads tid<32
  for (int i = tid; i < NBAT * HIDD; i += 256) h_s[i] = 0.f;
  __syncthreads();

  for (int t = 0; t < SLEN; t++) {
    if (t > 0) {
      // ---- gather h(t-1): 16 tagged u64 per thread, spin until fresh ----
      const unsigned want = (unsigned)(tagbase + t);
      const u64* src = Hx + (size_t)(want & 1) * (NBAT * HIDD);
      u64 v[16];
      #pragma unroll
      for (int r = 0; r < 16; r++)
        v[r] = __hip_atomic_load(src + tid + (r << 8),
                                 __ATOMIC_RELAXED, __HIP_MEMORY_SCOPE_AGENT);
      while (true) {
        unsigned stale = 0;
        #pragma unroll
        for (int r = 0; r < 16; r++)
          stale |= ((unsigned)(v[r] >> 32) != want) ? (1u << r) : 0u;
        if (stale == 0) break;
        __builtin_amdgcn_s_sleep(1);
        #pragma unroll
        for (int r = 0; r < 16; r++)
          if (stale & (1u << r))
            v[r] = __hip_atomic_load(src + tid + (r << 8),
                                     __ATOMIC_RELAXED, __HIP_MEMORY_SCOPE_AGENT);
      }
      __syncthreads();   // prev-step h_s consumers are done
      #pragma unroll
      for (int r = 0; r < 16; r++)
        h_s[tid + (r << 8)] = __uint_as_float((unsigned)v[r]);
      __syncthreads();   // h(t-1) ready in LDS
    }
    // ---- partial dots: a[cl*4+b] over this thread's 8 k values ----
    float4 ha[NBAT], hb[NBAT];
    #pragma unroll
    for (int b = 0; b < NBAT; b++) {
      ha[b] = ((const float4*)h_s)[b*256 + part];        // k = 4*part..+3
      hb[b] = ((const float4*)h_s)[b*256 + 128 + part];  // k = 512+4*part..+3
    }
    float a[64];
    #pragma unroll
    for (int cl = 0; cl < 16; cl++) {
      #pragma unroll
      for (int b = 0; b < NBAT; b++) {
        a[cl*4 + b] = Wf[cl].x*ha[b].x + Wf[cl].y*ha[b].y
                    + Wf[cl].z*ha[b].z + Wf[cl].w*ha[b].w
                    + Wg[cl].x*hb[b].x + Wg[cl].y*hb[b].y
                    + Wg[cl].z*hb[b].z + Wg[cl].w*hb[b].w;
      }
    }
    // ---- in-wave reduction: fold lanes 32..63, then 5 halving stages ----
    #pragma unroll
    for (int i = 0; i < 64; i++) a[i] += __shfl_xor(a[i], 32);
#define HALVE(MASK, SH, HSZ)                          \
    { const int bit_ = (lane >> SH) & 1;              \
      _Pragma("unroll")                               \
      for (int j = 0; j < HSZ; j++) {                 \
        float snd = bit_ ? a[j] : a[j + HSZ];         \
        float kep = bit_ ? a[j + HSZ] : a[j];         \
        a[j] = kep + __shfl_xor(snd, MASK);           \
      } }
    HALVE(1, 0, 32) HALVE(2, 1, 16) HALVE(4, 2, 8) HALVE(8, 3, 4) HALVE(16, 4, 2)
#undef HALVE
    if (lane < 32) {   // lane holds totals for acc idx rev5*2 and rev5*2+1
      z_s[w][rev5(lane)*2 + 0] = a[0];
      z_s[w][rev5(lane)*2 + 1] = a[1];
    }
    __syncthreads();
    if (tid < 128) {  // combine the two waves per ccH: zc[cc*4+b]
      const int cc = tid >> 2, b = tid & 3;
      const int cH = cc >> 4, i = ((cc & 15) << 2) | b;
      zc[tid] = z_s[2*cH][i] + z_s[2*cH + 1][i];
    }
    __syncthreads();
    if (tid < 32) {  // gates for (b, d): 8 units x 4 batches
      const int b = tid >> 3, d = tid & 7;
      const float* zrow = Z + (size_t)(b*SLEN + t) * GATE4;
      const float zi = zc[((0*8 + d) << 2) + b] + zrow[0*HIDD + hbase + d];
      const float zf = zc[((1*8 + d) << 2) + b] + zrow[1*HIDD + hbase + d];
      const float zg = zc[((2*8 + d) << 2) + b] + zrow[2*HIDD + hbase + d];
      const float zo = zc[((3*8 + d) << 2) + b] + zrow[3*HIDD + hbase + d];
      const float ig = 1.f / (1.f + expf(-zi));
      const float fg = 1.f / (1.f + expf(-zf));
      const float gg = tanhf(zg);
      const float og = 1.f / (1.f + expf(-zo));
      const float cn = fg * c_reg + ig * gg;
      const float hn = og * tanhf(cn);
      const bool mk = ids[b*SLEN + t] != 0;
      const float hp = h_s[b*HIDD + hbase + d];
      const float ho = mk ? hn : hp;
      c_reg = mk ? cn : c_reg;
      H[(size_t)(b*SLEN + t) * HIDD + hbase + d] = ho;
      // publish h(t) with tag (tagbase+t+1) into slot by tag parity
      const unsigned tg = (unsigned)(tagbase + t + 1);
      const u64 pk = ((u64)tg << 32) | (u64)__float_as_uint(ho);
      __hip_atomic_store(Hx + (size_t)(tg & 1) * (NBAT * HIDD)
                            + b * HIDD + hbase + d, pk,
                         __ATOMIC_RELAXED, __HIP_MEMORY_SCOPE_AGENT);
    }
    // no barrier: next iteration's gather spins on the tags
  }
}

extern "C" void kernel_launch(void* const* d_in, const int* in_sizes, int n_in,
                              void* d_out, int out_size, void* d_ws, size_t ws_size,
                              hipStream_t stream) {
  const int*   ids = (const int*)  d_in[0];
  const float* emb = (const float*)d_in[1];
  const float* Wk0 = (const float*)d_in[2];
  const float* Wr0 = (const float*)d_in[3];
  const float* b0  = (const float*)d_in[4];
  const float* Wk1 = (const float*)d_in[5];
  const float* Wr1 = (const float*)d_in[6];
  const float* b1  = (const float*)d_in[7];
  const float* Wp  = (const float*)d_in[8];
  const float* bp  = (const float*)d_in[9];
  float* out = (float*)d_out;

  // Intermediates that are DEAD before gemm_nt_logits launches live in the
  // head of d_out. Hx and P are live across kernels -> d_ws (~4.3 MB).
  float* X0   = out;                  // [2048,  512]  1,048,576 f
  float* Z    = out + 1048576;        // [2048, 4096]  8,388,608 f (reused L0/L1)
  float* H0   = out + 9437184;        // [2048, 1024]  2,097,152 f
  float* H1   = out + 11534336;       // [2048, 1024]  2,097,152 f
  float* WrT0 = out + 13631488;       // [4096, 1024]  4,194,304 f
  float* WrT1 = out + 17825792;       // [4096, 1024]  4,194,304 f
  u64*  Hx  = (u64*)d_ws;             // [2][4096] u64 = 64 KB (no init needed)
  float* P  = ((float*)d_ws) + 16384; // [2048, 512]  1,048,576 f = 4 MB

  embed_k<<<2048, 128, 0, stream>>>(ids, emb, X0);
  transpose_k<<<dim3(128, 32), 256, 0, stream>>>(Wr0, WrT0);
  transpose_k<<<dim3(128, 32), 256, 0, stream>>>(Wr1, WrT1);
  gemm_nn_bias<<<dim3(64, 32), 256, 0, stream>>>(X0, Wk0, b0, Z, 2048, 4096, 512);
  lstm_rec<<<LBLK, 256, 0, stream>>>(Z, WrT0, ids, H0, Hx, 0);
  gemm_nn_bias<<<dim3(64, 32), 256, 0, stream>>>(H0, Wk1, b1, Z, 2048, 4096, 1024);
  lstm_rec<<<LBLK, 256, 0, stream>>>(Z, WrT1, ids, H1, Hx, SLEN);
  gemm_nn_bias<<<dim3(8, 32), 256, 0, stream>>>(H1, Wp, bp, P, 2048, 512, 1024);
  gemm_nt_logits<<<dim3(500, 32), 256, 0, stream>>>(P, emb, ids, out);
}

// Round 5
// 9103.025 us; speedup vs baseline: 2.5265x; 1.0382x over previous
//
#include <hip/hip_runtime.h>

#define VOCAB 32000
#define EMBD  512
#define HIDD  1024
#define SLEN  512
#define NBAT  4
#define GATE4 4096   // 4*HIDD
#define LBLK  128    // lstm blocks; each owns UPB hidden units
#define UPB   8      // units per block

typedef unsigned long long u64;

// ---------------- embedding gather ----------------
__global__ void embed_k(const int* __restrict__ ids, const float* __restrict__ emb,
                        float* __restrict__ X0) {
  const int n  = blockIdx.x;             // 0..2047 (= b*SLEN + s)
  const int id = ids[n];
  ((float4*)X0)[(size_t)n*(EMBD/4) + threadIdx.x] =
      ((const float4*)emb)[(size_t)id*(EMBD/4) + threadIdx.x];
}

// ---------------- 32x32 tiled transpose: dst[c][r] = src[r][c] ----------------
// src [1024][4096] row-major -> dst [4096][1024]
__global__ __launch_bounds__(256) void transpose_k(const float* __restrict__ src,
                                                   float* __restrict__ dst) {
  __shared__ float t[32][33];
  const int bx = blockIdx.x * 32;   // col base (0..4095)
  const int by = blockIdx.y * 32;   // row base (0..1023)
  const int r0 = threadIdx.x >> 5;  // 0..7
  const int c  = threadIdx.x & 31;
  #pragma unroll
  for (int i = 0; i < 4; i++) {
    const int r = r0 + i*8;
    t[r][c] = src[(size_t)(by + r)*GATE4 + bx + c];
  }
  __syncthreads();
  #pragma unroll
  for (int i = 0; i < 4; i++) {
    const int rw = r0 + i*8;
    dst[(size_t)(bx + rw)*HIDD + by + c] = t[c][rw];
  }
}

// ---------------- f32 tiled GEMM: C = A@B + bias ----------------
// A [M,K] rm, B [K,N] rm, bias[N]; 64x64 tile, BK=16, 256 threads, 4x4/thread
__global__ __launch_bounds__(256) void gemm_nn_bias(
    const float* __restrict__ A, const float* __restrict__ B,
    const float* __restrict__ bias, float* __restrict__ C,
    int M, int N, int K) {
  __shared__ float As[16][64];
  __shared__ float Bs[16][64];
  const int tid = threadIdx.x;
  const int bm = blockIdx.y * 64;
  const int bn = blockIdx.x * 64;
  const int tx = tid & 15, ty = tid >> 4;
  const int mA = tid >> 2, kqA = (tid & 3) * 4;
  const int kB = tid >> 4, nB = (tid & 15) * 4;
  float acc[4][4] = {{0.f}};
  for (int k0 = 0; k0 < K; k0 += 16) {
    float4 a4 = *(const float4*)(A + (size_t)(bm + mA)*K + k0 + kqA);
    As[kqA+0][mA] = a4.x; As[kqA+1][mA] = a4.y;
    As[kqA+2][mA] = a4.z; As[kqA+3][mA] = a4.w;
    *(float4*)&Bs[kB][nB] = *(const float4*)(B + (size_t)(k0 + kB)*N + bn + nB);
    __syncthreads();
    #pragma unroll
    for (int k = 0; k < 16; k++) {
      float4 av = *(float4*)&As[k][ty*4];
      float4 bv = *(float4*)&Bs[k][tx*4];
      float ar[4] = {av.x, av.y, av.z, av.w};
      float br[4] = {bv.x, bv.y, bv.z, bv.w};
      #pragma unroll
      for (int i = 0; i < 4; i++)
        #pragma unroll
        for (int j = 0; j < 4; j++)
          acc[i][j] += ar[i] * br[j];
    }
    __syncthreads();
  }
  float4 bi = *(const float4*)(bias + bn + tx*4);
  #pragma unroll
  for (int i = 0; i < 4; i++) {
    float4 o;
    o.x = acc[i][0] + bi.x; o.y = acc[i][1] + bi.y;
    o.z = acc[i][2] + bi.z; o.w = acc[i][3] + bi.w;
    *(float4*)(C + (size_t)(bm + ty*4 + i)*N + bn + tx*4) = o;
  }
}

// ---------------- logits GEMM: C = A @ Bt^T, with pad-mask ----------------
__global__ __launch_bounds__(256) void gemm_nt_logits(
    const float* __restrict__ A,   // P [2048, 512] (in d_ws — must NOT alias C)
    const float* __restrict__ Bt,  // emb [32000, 512]
    const int* __restrict__ ids,   // [2048]
    float* __restrict__ C) {       // [2048, 32000]
  const int K = EMBD, N = VOCAB;
  __shared__ float As[16][64];
  __shared__ float Bs[16][64];
  const int tid = threadIdx.x;
  const int bm = blockIdx.y * 64;
  const int bn = blockIdx.x * 64;
  const int tx = tid & 15, ty = tid >> 4;
  const int rA = tid >> 2, kq = (tid & 3) * 4;
  float acc[4][4] = {{0.f}};
  for (int k0 = 0; k0 < K; k0 += 16) {
    float4 a4 = *(const float4*)(A  + (size_t)(bm + rA)*K + k0 + kq);
    float4 b4 = *(const float4*)(Bt + (size_t)(bn + rA)*K + k0 + kq);
    As[kq+0][rA] = a4.x; As[kq+1][rA] = a4.y; As[kq+2][rA] = a4.z; As[kq+3][rA] = a4.w;
    Bs[kq+0][rA] = b4.x; Bs[kq+1][rA] = b4.y; Bs[kq+2][rA] = b4.z; Bs[kq+3][rA] = b4.w;
    __syncthreads();
    #pragma unroll
    for (int k = 0; k < 16; k++) {
      float4 av = *(float4*)&As[k][ty*4];
      float4 bv = *(float4*)&Bs[k][tx*4];
      float ar[4] = {av.x, av.y, av.z, av.w};
      float br[4] = {bv.x, bv.y, bv.z, bv.w};
      #pragma unroll
      for (int i = 0; i < 4; i++)
        #pragma unroll
        for (int j = 0; j < 4; j++)
          acc[i][j] += ar[i] * br[j];
    }
    __syncthreads();
  }
  #pragma unroll
  for (int i = 0; i < 4; i++) {
    const int row = bm + ty*4 + i;
    const bool mk = ids[row] != 0;
    float4 o;
    if (mk) { o.x = acc[i][0]; o.y = acc[i][1]; o.z = acc[i][2]; o.w = acc[i][3]; }
    else    { o.x = (bn + tx*4 == 0) ? 1.f : 0.f; o.y = 0.f; o.z = 0.f; o.w = 0.f; }
    *(float4*)(C + (size_t)row*N + bn + tx*4) = o;
  }
}

// ---------------- persistent LSTM recurrence (counter + bulk gather) --------
// LBLK=128 blocks x 256 threads; block j owns hidden units [8j, 8j+8) ->
// 32 gate columns of Wr in VGPRs. Per step: publish 32 f32 h-values with
// relaxed agent-scope stores; __syncthreads() (emits s_waitcnt vmcnt(0) ->
// stores globally retired); ONE relaxed fetch_add on the layer counter.
// Readers poll the 4-byte counter (1 lane/block), then bulk-gather h(t-1)
// once. No fences, no tag re-reads. Two slots by step parity: a producer
// reaching step t+2 implies all blocks finished gathering h(t).
__device__ __forceinline__ int rev5(int l) {
  return ((l & 1) << 4) | ((l & 2) << 2) | (l & 4) | ((l & 8) >> 2) | ((l & 16) >> 4);
}

__global__ __launch_bounds__(256, 1) void lstm_rec(
    const float* __restrict__ Z,    // [B*S, 4096] precomputed x@Wk + b
    const float* __restrict__ WrT,  // [4096, 1024] transposed recurrent weights
    const int* __restrict__ ids,    // [B*S]
    float* __restrict__ H,          // [B*S, 1024] output h sequence
    float* __restrict__ Hx,         // [2][NBAT*HIDD] h exchange (this layer)
    unsigned* __restrict__ cnt) {   // this layer's counter (zeroed on launch)
  __shared__ float h_s[NBAT * HIDD];   // [b][k]
  __shared__ float z_s[4][64];
  __shared__ float zc[128];            // [cc][b]  cc=0..31, b=0..3
  const int tid  = threadIdx.x;
  const int lane = tid & 63;
  const int w    = tid >> 6;
  const int ccH  = tid >> 7;           // 0..1  (which 16 of the 32 gate cols)
  const int part = tid & 127;          // 0..127 (k-slice owner: 8 k values)
  const int hbase = blockIdx.x * UPB;

  // --- coalesced load of this block's 32 WrT rows into registers ---
  float4 Wf[16], Wg[16];
  #pragma unroll
  for (int cl = 0; cl < 16; cl++) {
    const int cc  = ccH * 16 + cl;
    const int g   = cc >> 3, d = cc & 7;
    const size_t col = (size_t)(g * HIDD + hbase + d);
    Wf[cl] = *(const float4*)(WrT + col * HIDD + 4 * part);
    Wg[cl] = *(const float4*)(WrT + col * HIDD + 512 + 4 * part);
  }
  float c_reg = 0.f;   // cell state, meaningful in threads tid<32
  for (int i = tid; i < NBAT * HIDD; i += 256) h_s[i] = 0.f;
  __syncthreads();

  for (int t = 0; t < SLEN; t++) {
    // ---- prefetch this step's gate biases (Z) + mask off the critical path
    float pz0 = 0.f, pz1 = 0.f, pz2 = 0.f, pz3 = 0.f;
    int pmk = 0;
    if (tid < 32) {
      const int b = tid >> 3, d = tid & 7;
      const float* zrow = Z + (size_t)(b*SLEN + t) * GATE4 + hbase + d;
      pz0 = zrow[0*HIDD]; pz1 = zrow[1*HIDD];
      pz2 = zrow[2*HIDD]; pz3 = zrow[3*HIDD];
      pmk = ids[b*SLEN + t];
    }
    if (t > 0) {
      // ---- wait until all blocks published h(t-1): poll ONE u32 ----
      if (tid == 0) {
        while (__hip_atomic_load(cnt, __ATOMIC_RELAXED,
                                 __HIP_MEMORY_SCOPE_AGENT) < 128u * (unsigned)t)
          __builtin_amdgcn_s_sleep(1);
      }
      __syncthreads();   // all threads: h(t-1) ready; prev h_s readers done
      // ---- bulk gather h(t-1), once ----
      const float* src = Hx + (size_t)((t - 1) & 1) * (NBAT * HIDD);
      float v[16];
      #pragma unroll
      for (int r = 0; r < 16; r++)
        v[r] = __hip_atomic_load(src + tid + (r << 8),
                                 __ATOMIC_RELAXED, __HIP_MEMORY_SCOPE_AGENT);
      #pragma unroll
      for (int r = 0; r < 16; r++)
        h_s[tid + (r << 8)] = v[r];
      __syncthreads();   // h(t-1) staged in LDS
    }
    // ---- partial dots: a[cl*4+b] over this thread's 8 k values ----
    float4 ha[NBAT], hb[NBAT];
    #pragma unroll
    for (int b = 0; b < NBAT; b++) {
      ha[b] = ((const float4*)h_s)[b*256 + part];        // k = 4*part..+3
      hb[b] = ((const float4*)h_s)[b*256 + 128 + part];  // k = 512+4*part..+3
    }
    float a[64];
    #pragma unroll
    for (int cl = 0; cl < 16; cl++) {
      #pragma unroll
      for (int b = 0; b < NBAT; b++) {
        a[cl*4 + b] = Wf[cl].x*ha[b].x + Wf[cl].y*ha[b].y
                    + Wf[cl].z*ha[b].z + Wf[cl].w*ha[b].w
                    + Wg[cl].x*hb[b].x + Wg[cl].y*hb[b].y
                    + Wg[cl].z*hb[b].z + Wg[cl].w*hb[b].w;
      }
    }
    // ---- in-wave reduction: fold lanes 32..63, then 5 halving stages ----
    #pragma unroll
    for (int i = 0; i < 64; i++) a[i] += __shfl_xor(a[i], 32);
#define HALVE(MASK, SH, HSZ)                          \
    { const int bit_ = (lane >> SH) & 1;              \
      _Pragma("unroll")                               \
      for (int j = 0; j < HSZ; j++) {                 \
        float snd = bit_ ? a[j] : a[j + HSZ];         \
        float kep = bit_ ? a[j + HSZ] : a[j];         \
        a[j] = kep + __shfl_xor(snd, MASK);           \
      } }
    HALVE(1, 0, 32) HALVE(2, 1, 16) HALVE(4, 2, 8) HALVE(8, 3, 4) HALVE(16, 4, 2)
#undef HALVE
    if (lane < 32) {   // lane holds totals for acc idx rev5*2 and rev5*2+1
      z_s[w][rev5(lane)*2 + 0] = a[0];
      z_s[w][rev5(lane)*2 + 1] = a[1];
    }
    __syncthreads();
    if (tid < 128) {  // combine the two waves per ccH: zc[cc*4+b]
      const int cc = tid >> 2, b = tid & 3;
      const int cH = cc >> 4, i = ((cc & 15) << 2) | b;
      zc[tid] = z_s[2*cH][i] + z_s[2*cH + 1][i];
    }
    __syncthreads();
    if (tid < 32) {  // gates for (b, d): 8 units x 4 batches
      const int b = tid >> 3, d = tid & 7;
      const float zi = zc[((0*8 + d) << 2) + b] + pz0;
      const float zf = zc[((1*8 + d) << 2) + b] + pz1;
      const float zg = zc[((2*8 + d) << 2) + b] + pz2;
      const float zo = zc[((3*8 + d) << 2) + b] + pz3;
      const float ig = 1.f / (1.f + expf(-zi));
      const float fg = 1.f / (1.f + expf(-zf));
      const float gg = tanhf(zg);
      const float og = 1.f / (1.f + expf(-zo));
      const float cn = fg * c_reg + ig * gg;
      const float hn = og * tanhf(cn);
      const bool mk = pmk != 0;
      const float hp = h_s[b*HIDD + hbase + d];
      const float ho = mk ? hn : hp;
      c_reg = mk ? cn : c_reg;
      H[(size_t)(b*SLEN + t) * HIDD + hbase + d] = ho;
      if (t < SLEN - 1) {  // publish h(t) into slot t&1 (relaxed, no fence)
        __hip_atomic_store(Hx + (size_t)(t & 1) * (NBAT * HIDD)
                              + b * HIDD + hbase + d, ho,
                           __ATOMIC_RELAXED, __HIP_MEMORY_SCOPE_AGENT);
      }
    }
    if (t == SLEN - 1) break;
    __syncthreads();   // s_waitcnt vmcnt(0) before barrier: stores retired
    if (tid == 0)
      __hip_atomic_fetch_add(cnt, 1u, __ATOMIC_RELAXED,
                             __HIP_MEMORY_SCOPE_AGENT);
  }
}

extern "C" void kernel_launch(void* const* d_in, const int* in_sizes, int n_in,
                              void* d_out, int out_size, void* d_ws, size_t ws_size,
                              hipStream_t stream) {
  const int*   ids = (const int*)  d_in[0];
  const float* emb = (const float*)d_in[1];
  const float* Wk0 = (const float*)d_in[2];
  const float* Wr0 = (const float*)d_in[3];
  const float* b0  = (const float*)d_in[4];
  const float* Wk1 = (const float*)d_in[5];
  const float* Wr1 = (const float*)d_in[6];
  const float* b1  = (const float*)d_in[7];
  const float* Wp  = (const float*)d_in[8];
  const float* bp  = (const float*)d_in[9];
  float* out = (float*)d_out;

  // Intermediates that are DEAD before gemm_nt_logits launches live in the
  // head of d_out. Counters/Hx/P are live across kernels -> d_ws (~4.3 MB).
  float* X0   = out;                  // [2048,  512]  1,048,576 f
  float* Z    = out + 1048576;        // [2048, 4096]  8,388,608 f (reused L0/L1)
  float* H0   = out + 9437184;        // [2048, 1024]  2,097,152 f
  float* H1   = out + 11534336;       // [2048, 1024]  2,097,152 f
  float* WrT0 = out + 13631488;       // [4096, 1024]  4,194,304 f
  float* WrT1 = out + 17825792;       // [4096, 1024]  4,194,304 f
  unsigned* cnt0 = (unsigned*)d_ws;                  // +0    (64B line)
  unsigned* cnt1 = (unsigned*)d_ws + 64;             // +256B
  float* Hx0 = ((float*)d_ws) + 256;  // [2][4096] f32 = 32 KB
  float* Hx1 = Hx0 + 8192;            // [2][4096] f32 = 32 KB
  float* P   = ((float*)d_ws) + 32768; // [2048, 512] 1,048,576 f = 4 MB

  hipMemsetAsync(d_ws, 0, 1024, stream);  // zero both counters each launch
  embed_k<<<2048, 128, 0, stream>>>(ids, emb, X0);
  transpose_k<<<dim3(128, 32), 256, 0, stream>>>(Wr0, WrT0);
  transpose_k<<<dim3(128, 32), 256, 0, stream>>>(Wr1, WrT1);
  gemm_nn_bias<<<dim3(64, 32), 256, 0, stream>>>(X0, Wk0, b0, Z, 2048, 4096, 512);
  lstm_rec<<<LBLK, 256, 0, stream>>>(Z, WrT0, ids, H0, Hx0, cnt0);
  gemm_nn_bias<<<dim3(64, 32), 256, 0, stream>>>(H0, Wk1, b1, Z, 2048, 4096, 1024);
  lstm_rec<<<LBLK, 256, 0, stream>>>(Z, WrT1, ids, H1, Hx1, cnt1);
  gemm_nn_bias<<<dim3(8, 32), 256, 0, stream>>>(H1, Wp, bp, P, 2048, 512, 1024);
  gemm_nt_logits<<<dim3(500, 32), 256, 0, stream>>>(P, emb, ids, out);
}

// Round 6
// 8144.752 us; speedup vs baseline: 2.8238x; 1.1177x over previous
//
#include <hip/hip_runtime.h>

#define VOCAB 32000
#define EMBD  512
#define HIDD  1024
#define SLEN  512
#define NBAT  4
#define GATE4 4096   // 4*HIDD
#define LBLK  128    // lstm blocks; each owns UPB hidden units
#define UPB   8      // units per block

typedef unsigned long long u64;

// ---------------- embedding gather ----------------
__global__ void embed_k(const int* __restrict__ ids, const float* __restrict__ emb,
                        float* __restrict__ X0) {
  const int n  = blockIdx.x;             // 0..2047 (= b*SLEN + s)
  const int id = ids[n];
  ((float4*)X0)[(size_t)n*(EMBD/4) + threadIdx.x] =
      ((const float4*)emb)[(size_t)id*(EMBD/4) + threadIdx.x];
}

// ---------------- 32x32 tiled transpose: dst[c][r] = src[r][c] ----------------
// src [1024][4096] row-major -> dst [4096][1024]
__global__ __launch_bounds__(256) void transpose_k(const float* __restrict__ src,
                                                   float* __restrict__ dst) {
  __shared__ float t[32][33];
  const int bx = blockIdx.x * 32;   // col base (0..4095)
  const int by = blockIdx.y * 32;   // row base (0..1023)
  const int r0 = threadIdx.x >> 5;  // 0..7
  const int c  = threadIdx.x & 31;
  #pragma unroll
  for (int i = 0; i < 4; i++) {
    const int r = r0 + i*8;
    t[r][c] = src[(size_t)(by + r)*GATE4 + bx + c];
  }
  __syncthreads();
  #pragma unroll
  for (int i = 0; i < 4; i++) {
    const int rw = r0 + i*8;
    dst[(size_t)(bx + rw)*HIDD + by + c] = t[c][rw];
  }
}

// ---------------- f32 tiled GEMM: C = A@B + bias ----------------
// A [M,K] rm, B [K,N] rm, bias[N]; 64x64 tile, BK=16, 256 threads, 4x4/thread
__global__ __launch_bounds__(256) void gemm_nn_bias(
    const float* __restrict__ A, const float* __restrict__ B,
    const float* __restrict__ bias, float* __restrict__ C,
    int M, int N, int K) {
  __shared__ float As[16][64];
  __shared__ float Bs[16][64];
  const int tid = threadIdx.x;
  const int bm = blockIdx.y * 64;
  const int bn = blockIdx.x * 64;
  const int tx = tid & 15, ty = tid >> 4;
  const int mA = tid >> 2, kqA = (tid & 3) * 4;
  const int kB = tid >> 4, nB = (tid & 15) * 4;
  float acc[4][4] = {{0.f}};
  for (int k0 = 0; k0 < K; k0 += 16) {
    float4 a4 = *(const float4*)(A + (size_t)(bm + mA)*K + k0 + kqA);
    As[kqA+0][mA] = a4.x; As[kqA+1][mA] = a4.y;
    As[kqA+2][mA] = a4.z; As[kqA+3][mA] = a4.w;
    *(float4*)&Bs[kB][nB] = *(const float4*)(B + (size_t)(k0 + kB)*N + bn + nB);
    __syncthreads();
    #pragma unroll
    for (int k = 0; k < 16; k++) {
      float4 av = *(float4*)&As[k][ty*4];
      float4 bv = *(float4*)&Bs[k][tx*4];
      float ar[4] = {av.x, av.y, av.z, av.w};
      float br[4] = {bv.x, bv.y, bv.z, bv.w};
      #pragma unroll
      for (int i = 0; i < 4; i++)
        #pragma unroll
        for (int j = 0; j < 4; j++)
          acc[i][j] += ar[i] * br[j];
    }
    __syncthreads();
  }
  float4 bi = *(const float4*)(bias + bn + tx*4);
  #pragma unroll
  for (int i = 0; i < 4; i++) {
    float4 o;
    o.x = acc[i][0] + bi.x; o.y = acc[i][1] + bi.y;
    o.z = acc[i][2] + bi.z; o.w = acc[i][3] + bi.w;
    *(float4*)(C + (size_t)(bm + ty*4 + i)*N + bn + tx*4) = o;
  }
}

// ---------------- logits GEMM: C = A @ Bt^T, with pad-mask ----------------
__global__ __launch_bounds__(256) void gemm_nt_logits(
    const float* __restrict__ A,   // P [2048, 512] (in d_ws — must NOT alias C)
    const float* __restrict__ Bt,  // emb [32000, 512]
    const int* __restrict__ ids,   // [2048]
    float* __restrict__ C) {       // [2048, 32000]
  const int K = EMBD, N = VOCAB;
  __shared__ float As[16][64];
  __shared__ float Bs[16][64];
  const int tid = threadIdx.x;
  const int bm = blockIdx.y * 64;
  const int bn = blockIdx.x * 64;
  const int tx = tid & 15, ty = tid >> 4;
  const int rA = tid >> 2, kq = (tid & 3) * 4;
  float acc[4][4] = {{0.f}};
  for (int k0 = 0; k0 < K; k0 += 16) {
    float4 a4 = *(const float4*)(A  + (size_t)(bm + rA)*K + k0 + kq);
    float4 b4 = *(const float4*)(Bt + (size_t)(bn + rA)*K + k0 + kq);
    As[kq+0][rA] = a4.x; As[kq+1][rA] = a4.y; As[kq+2][rA] = a4.z; As[kq+3][rA] = a4.w;
    Bs[kq+0][rA] = b4.x; Bs[kq+1][rA] = b4.y; Bs[kq+2][rA] = b4.z; Bs[kq+3][rA] = b4.w;
    __syncthreads();
    #pragma unroll
    for (int k = 0; k < 16; k++) {
      float4 av = *(float4*)&As[k][ty*4];
      float4 bv = *(float4*)&Bs[k][tx*4];
      float ar[4] = {av.x, av.y, av.z, av.w};
      float br[4] = {bv.x, bv.y, bv.z, bv.w};
      #pragma unroll
      for (int i = 0; i < 4; i++)
        #pragma unroll
        for (int j = 0; j < 4; j++)
          acc[i][j] += ar[i] * br[j];
    }
    __syncthreads();
  }
  #pragma unroll
  for (int i = 0; i < 4; i++) {
    const int row = bm + ty*4 + i;
    const bool mk = ids[row] != 0;
    float4 o;
    if (mk) { o.x = acc[i][0]; o.y = acc[i][1]; o.z = acc[i][2]; o.w = acc[i][3]; }
    else    { o.x = (bn + tx*4 == 0) ? 1.f : 0.f; o.y = 0.f; o.z = 0.f; o.w = 0.f; }
    *(float4*)(C + (size_t)row*N + bn + tx*4) = o;
  }
}

// ---------------- persistent LSTM recurrence (distributed relaxed flags) ----
// LBLK=128 blocks x 256 threads; block j owns hidden units [8j, 8j+8) ->
// 32 gate columns of Wr in VGPRs. Per step, producer wave 0:
//   32 relaxed h stores -> s_waitcnt vmcnt(0) (wave-scoped; h at coherence
//   point) -> ONE relaxed store flag[bid]=t+1. No RMW, no fences.
// Readers: 128 threads each spin on their own padded flag line, then
// __syncthreads(), then one bulk u64 gather of h(t-1). Two slots by step
// parity: flag=t+2 from a block implies its slot-t gather completed.
__device__ __forceinline__ int rev5(int l) {
  return ((l & 1) << 4) | ((l & 2) << 2) | (l & 4) | ((l & 8) >> 2) | ((l & 16) >> 4);
}

__global__ __launch_bounds__(256, 1) void lstm_rec(
    const float* __restrict__ Z,    // [B*S, 4096] precomputed x@Wk + b
    const float* __restrict__ WrT,  // [4096, 1024] transposed recurrent weights
    const int* __restrict__ ids,    // [B*S]
    float* __restrict__ H,          // [B*S, 1024] output h sequence
    float* __restrict__ Hx,         // [2][NBAT*HIDD] h exchange (this layer)
    unsigned* __restrict__ flags) { // [LBLK*16] padded flags (zeroed at launch)
  __shared__ float h_s[NBAT * HIDD];   // [b][k]
  __shared__ float z_s[4][64];
  __shared__ float zc[128];            // [cc][b]  cc=0..31, b=0..3
  const int tid  = threadIdx.x;
  const int lane = tid & 63;
  const int w    = tid >> 6;
  const int ccH  = tid >> 7;           // 0..1  (which 16 of the 32 gate cols)
  const int part = tid & 127;          // 0..127 (k-slice owner: 8 k values)
  const int hbase = blockIdx.x * UPB;

  // --- coalesced load of this block's 32 WrT rows into registers ---
  float4 Wf[16], Wg[16];
  #pragma unroll
  for (int cl = 0; cl < 16; cl++) {
    const int cc  = ccH * 16 + cl;
    const int g   = cc >> 3, d = cc & 7;
    const size_t col = (size_t)(g * HIDD + hbase + d);
    Wf[cl] = *(const float4*)(WrT + col * HIDD + 4 * part);
    Wg[cl] = *(const float4*)(WrT + col * HIDD + 512 + 4 * part);
  }
  float c_reg = 0.f;   // cell state, meaningful in threads tid<32
  for (int i = tid; i < NBAT * HIDD; i += 256) h_s[i] = 0.f;
  __syncthreads();

  for (int t = 0; t < SLEN; t++) {
    // ---- prefetch this step's gate biases (Z) + mask off the critical path
    float pz0 = 0.f, pz1 = 0.f, pz2 = 0.f, pz3 = 0.f;
    int pmk = 0;
    if (tid < 32) {
      const int b = tid >> 3, d = tid & 7;
      const float* zrow = Z + (size_t)(b*SLEN + t) * GATE4 + hbase + d;
      pz0 = zrow[0*HIDD]; pz1 = zrow[1*HIDD];
      pz2 = zrow[2*HIDD]; pz3 = zrow[3*HIDD];
      pmk = ids[b*SLEN + t];
    }
    if (t > 0) {
      // ---- wait: 128 threads each spin on their own block's flag ----
      if (tid < LBLK) {
        while (__hip_atomic_load(flags + tid * 16, __ATOMIC_RELAXED,
                                 __HIP_MEMORY_SCOPE_AGENT) < (unsigned)t)
          __builtin_amdgcn_s_sleep(1);
      }
      __syncthreads();   // all flags seen; prev h_s readers also done
      // ---- bulk gather h(t-1) as u64 pairs, once ----
      const u64* src = (const u64*)(Hx + (size_t)((t - 1) & 1) * (NBAT * HIDD));
      u64 v[8];
      #pragma unroll
      for (int r = 0; r < 8; r++)
        v[r] = __hip_atomic_load(src + tid + (r << 8),
                                 __ATOMIC_RELAXED, __HIP_MEMORY_SCOPE_AGENT);
      #pragma unroll
      for (int r = 0; r < 8; r++)
        ((u64*)h_s)[tid + (r << 8)] = v[r];
      __syncthreads();   // h(t-1) staged in LDS
    }
    // ---- partial dots: a[cl*4+b] over this thread's 8 k values ----
    float4 ha[NBAT], hb[NBAT];
    #pragma unroll
    for (int b = 0; b < NBAT; b++) {
      ha[b] = ((const float4*)h_s)[b*256 + part];        // k = 4*part..+3
      hb[b] = ((const float4*)h_s)[b*256 + 128 + part];  // k = 512+4*part..+3
    }
    float a[64];
    #pragma unroll
    for (int cl = 0; cl < 16; cl++) {
      #pragma unroll
      for (int b = 0; b < NBAT; b++) {
        a[cl*4 + b] = Wf[cl].x*ha[b].x + Wf[cl].y*ha[b].y
                    + Wf[cl].z*ha[b].z + Wf[cl].w*ha[b].w
                    + Wg[cl].x*hb[b].x + Wg[cl].y*hb[b].y
                    + Wg[cl].z*hb[b].z + Wg[cl].w*hb[b].w;
      }
    }
    // ---- in-wave reduction: fold lanes 32..63, then 5 halving stages ----
    #pragma unroll
    for (int i = 0; i < 64; i++) a[i] += __shfl_xor(a[i], 32);
#define HALVE(MASK, SH, HSZ)                          \
    { const int bit_ = (lane >> SH) & 1;              \
      _Pragma("unroll")                               \
      for (int j = 0; j < HSZ; j++) {                 \
        float snd = bit_ ? a[j] : a[j + HSZ];         \
        float kep = bit_ ? a[j + HSZ] : a[j];         \
        a[j] = kep + __shfl_xor(snd, MASK);           \
      } }
    HALVE(1, 0, 32) HALVE(2, 1, 16) HALVE(4, 2, 8) HALVE(8, 3, 4) HALVE(16, 4, 2)
#undef HALVE
    if (lane < 32) {   // lane holds totals for acc idx rev5*2 and rev5*2+1
      z_s[w][rev5(lane)*2 + 0] = a[0];
      z_s[w][rev5(lane)*2 + 1] = a[1];
    }
    __syncthreads();
    if (tid < 128) {  // combine the two waves per ccH: zc[cc*4+b]
      const int cc = tid >> 2, b = tid & 3;
      const int cH = cc >> 4, i = ((cc & 15) << 2) | b;
      zc[tid] = z_s[2*cH][i] + z_s[2*cH + 1][i];
    }
    __syncthreads();
    if (tid < 32) {  // gates for (b, d): 8 units x 4 batches
      const int b = tid >> 3, d = tid & 7;
      const float zi = zc[((0*8 + d) << 2) + b] + pz0;
      const float zf = zc[((1*8 + d) << 2) + b] + pz1;
      const float zg = zc[((2*8 + d) << 2) + b] + pz2;
      const float zo = zc[((3*8 + d) << 2) + b] + pz3;
      const float ig = 1.f / (1.f + expf(-zi));
      const float fg = 1.f / (1.f + expf(-zf));
      const float gg = tanhf(zg);
      const float og = 1.f / (1.f + expf(-zo));
      const float cn = fg * c_reg + ig * gg;
      const float hn = og * tanhf(cn);
      const bool mk = pmk != 0;
      const float hp = h_s[b*HIDD + hbase + d];
      const float ho = mk ? hn : hp;
      c_reg = mk ? cn : c_reg;
      H[(size_t)(b*SLEN + t) * HIDD + hbase + d] = ho;
      if (t < SLEN - 1) {  // publish h(t) into slot t&1 (relaxed, no fence)
        __hip_atomic_store(Hx + (size_t)(t & 1) * (NBAT * HIDD)
                              + b * HIDD + hbase + d, ho,
                           __ATOMIC_RELAXED, __HIP_MEMORY_SCOPE_AGENT);
      }
    }
    if (t == SLEN - 1) break;
    // ---- publish readiness: wave 0 only (producers all live in wave 0) ----
    if (w == 0) {
      asm volatile("s_waitcnt vmcnt(0)" ::: "memory");  // h stores retired
      if (tid == 0)
        __hip_atomic_store(flags + blockIdx.x * 16, (unsigned)(t + 1),
                           __ATOMIC_RELAXED, __HIP_MEMORY_SCOPE_AGENT);
    }
  }
}

extern "C" void kernel_launch(void* const* d_in, const int* in_sizes, int n_in,
                              void* d_out, int out_size, void* d_ws, size_t ws_size,
                              hipStream_t stream) {
  const int*   ids = (const int*)  d_in[0];
  const float* emb = (const float*)d_in[1];
  const float* Wk0 = (const float*)d_in[2];
  const float* Wr0 = (const float*)d_in[3];
  const float* b0  = (const float*)d_in[4];
  const float* Wk1 = (const float*)d_in[5];
  const float* Wr1 = (const float*)d_in[6];
  const float* b1  = (const float*)d_in[7];
  const float* Wp  = (const float*)d_in[8];
  const float* bp  = (const float*)d_in[9];
  float* out = (float*)d_out;

  // Intermediates that are DEAD before gemm_nt_logits launches live in the
  // head of d_out. Flags/Hx/P live across kernels -> d_ws (~4.3 MB).
  float* X0   = out;                  // [2048,  512]  1,048,576 f
  float* Z    = out + 1048576;        // [2048, 4096]  8,388,608 f (reused L0/L1)
  float* H0   = out + 9437184;        // [2048, 1024]  2,097,152 f
  float* H1   = out + 11534336;       // [2048, 1024]  2,097,152 f
  float* WrT0 = out + 13631488;       // [4096, 1024]  4,194,304 f
  float* WrT1 = out + 17825792;       // [4096, 1024]  4,194,304 f
  unsigned* flg0 = (unsigned*)d_ws;            // [128*16] u32 = 8 KB
  unsigned* flg1 = (unsigned*)d_ws + 2048;     // [128*16] u32 = 8 KB
  float* Hx0 = ((float*)d_ws) + 4096;  // [2][4096] f32 = 32 KB
  float* Hx1 = Hx0 + 8192;             // [2][4096] f32 = 32 KB
  float* P   = ((float*)d_ws) + 20480; // [2048, 512] 1,048,576 f = 4 MB

  hipMemsetAsync(d_ws, 0, 16384, stream);  // zero both flag arrays
  embed_k<<<2048, 128, 0, stream>>>(ids, emb, X0);
  transpose_k<<<dim3(128, 32), 256, 0, stream>>>(Wr0, WrT0);
  transpose_k<<<dim3(128, 32), 256, 0, stream>>>(Wr1, WrT1);
  gemm_nn_bias<<<dim3(64, 32), 256, 0, stream>>>(X0, Wk0, b0, Z, 2048, 4096, 512);
  lstm_rec<<<LBLK, 256, 0, stream>>>(Z, WrT0, ids, H0, Hx0, flg0);
  gemm_nn_bias<<<dim3(64, 32), 256, 0, stream>>>(H0, Wk1, b1, Z, 2048, 4096, 1024);
  lstm_rec<<<LBLK, 256, 0, stream>>>(Z, WrT1, ids, H1, Hx1, flg1);
  gemm_nn_bias<<<dim3(8, 32), 256, 0, stream>>>(H1, Wp, bp, P, 2048, 512, 1024);
  gemm_nt_logits<<<dim3(500, 32), 256, 0, stream>>>(P, emb, ids, out);
}